// Round 6
// baseline (218.691 us; speedup 1.0000x reference)
//
#include <hip/hip_runtime.h>
#include <math.h>

// ---------------- static problem structure (LMAX=4, taus=16) ----------------
#define NTRI 42
#define NCH  10752
#define B_SZ 256

// runtime copies (for k_init)
__constant__ int TL[NTRI]  = {0,0,0,0,0, 1,1,1,1,1,1,1,1, 2,2,2,2,2,2,2,2,2,2, 3,3,3,3,3,3,3,3,3,3, 4,4,4,4,4,4,4,4,4};
__constant__ int TL1[NTRI] = {0,1,2,3,4, 1,1,2,2,3,3,4,4, 1,2,2,2,3,3,3,4,4,4, 2,2,3,3,3,3,4,4,4,4, 2,3,3,3,4,4,4,4,4};
__constant__ int TL2[NTRI] = {0,1,2,3,4, 0,1,1,2,2,3,3,4, 1,0,1,2,1,2,3,2,3,4, 1,2,0,1,2,3,1,2,3,4, 2,1,2,3,0,1,2,3,4};

// compile-time copies (sorted by (l,l1,l2)); CT_T = tile index within degree l
constexpr int CT_L [NTRI]={0,0,0,0,0, 1,1,1,1,1,1,1,1, 2,2,2,2,2,2,2,2,2,2, 3,3,3,3,3,3,3,3,3,3, 4,4,4,4,4,4,4,4,4};
constexpr int CT_L1[NTRI]={0,1,2,3,4, 1,1,2,2,3,3,4,4, 1,2,2,2,3,3,3,4,4,4, 2,2,3,3,3,3,4,4,4,4, 2,3,3,3,4,4,4,4,4};
constexpr int CT_L2[NTRI]={0,1,2,3,4, 0,1,1,2,2,3,3,4, 1,0,1,2,1,2,3,2,3,4, 1,2,0,1,2,3,1,2,3,4, 2,1,2,3,0,1,2,3,4};
constexpr int CT_T [NTRI]={0,1,2,3,4, 0,1,2,3,4,5,6,7, 0,1,2,3,4,5,6,7,8,9, 0,1,2,3,4,5,6,7,8,9, 0,1,2,3,4,5,6,7,8};

constexpr int KL_t[5]    ={1280,2048,2560,2560,2304};   // t_FF[l]
constexpr int GBASE_t[5] ={0,1280,3328,5888,8448};      // channel base
constexpr int ROFF_t[5]  ={0,16,64,144,256};            // row offset in 400-row layout
constexpr int WOFF_t[5]  ={0,20480,53248,94208,135168}; // complex offset into W
constexpr int NT_t[5]    ={5,8,10,10,9};                // tiles per l
// partials: g_part[PBASE[l] + b*PSTR[l] + T*16*NM + o*NM + m]
constexpr int PSTR_t[5]  ={80,384,800,1120,1296};       // NT*16*NM
constexpr int PBASE_t[5] ={0,20480,118784,323584,610304};
#define PART_TOT 942080

// runtime copies for k_red
__constant__ int ROFFc[5]={0,16,64,144,256};
__constant__ int NTc[5]  ={5,8,10,10,9};
__constant__ int NMc[5]  ={1,3,5,7,9};
__constant__ int PSTRc[5]={80,384,800,1120,1296};
__constant__ int PBASEc[5]={0,20480,118784,323584,610304};

// ---------------- device globals ----------------
__device__ float  g_varsum[NCH];
__device__ float  g_cgcD[NTRI][81];   // dense CG: slot = mi*n1 + p (0 if invalid)
__device__ float2 g_part[PART_TOT];   // 7.4 MB per-tile output partials

// ---------------- CG coefficient via factorial table (fp64) ----------------
__device__ double cg_coefT(const double* F, int j1,int m1,int j2,int m2,int j,int m){
    if(m1+m2!=m) return 0.0;
    double pref = sqrt((2.0*j+1.0)*F[j+j1-j2]*F[j-j1+j2]*F[j1+j2-j]/F[j1+j2+j+1]);
    pref *= sqrt(F[j+m]*F[j-m]*F[j1-m1]*F[j1+m1]*F[j2-m2]*F[j2+m2]);
    double s=0.0;
    for(int k=0;k<=j1+j2-j;k++){
        int a=j1-m1-k, bb=j2+m2-k, c=j-j2+m1+k, d=j-j1-m2+k;
        if(a<0||bb<0||c<0||d<0) continue;
        double term = 1.0/(F[k]*F[j1+j2-j-k]*F[a]*F[bb]*F[c]*F[d]);
        s += (k&1)? -term : term;
    }
    return pref*s;
}

// ------- kernel 1: init — zero varsum + build dense CG tables -----------------
__global__ void k_init(){
    __shared__ double fact[20];
    const int tr=blockIdx.x, t=threadIdx.x;
    if(t==0){ double r=1.0; fact[0]=1.0; for(int i=1;i<20;i++){ r*=(double)i; fact[i]=r; } }
    g_varsum[tr*256+t]=0.f;                           // NCH == 42*256 exactly
    __syncthreads();
    const int l=TL[tr], l1=TL1[tr], l2=TL2[tr];
    const int nm=2*l+1, n1=2*l1+1;
    if(t < nm*n1){
        const int mi=t/n1, p=t%n1;
        const int m=mi-l, m1=p-l1, m2=m-m1;
        float c=0.f;
        if(m2>=-l2 && m2<=l2) c=(float)cg_coefT(fact,l1,m1,l2,m2,l,m);
        g_cgcD[tr][t]=c;
    }
}

// ---------------- CG product in registers: thread = pair (i,j) ----------------
template<int L,int L1,int L2>
__device__ __forceinline__ void cg_compute(const float2* __restrict__ FsB,
                                           const float* __restrict__ cg,
                                           int i, int j, float2 (&ff)[2*L+1]){
    constexpr int N1=2*L1+1, N2=2*L2+1, NM=2*L+1;
    float2 A[N1], Bv[N2];
    #pragma unroll
    for(int p=0;p<N1;p++) A[p]=FsB[ROFF_t[L1]+i*N1+p];
    #pragma unroll
    for(int q=0;q<N2;q++) Bv[q]=FsB[ROFF_t[L2]+j*N2+q];
    #pragma unroll
    for(int mi=0;mi<NM;mi++){
        float aR=0.f, aI=0.f;
        const int pLo = (mi-L+L1-L2) > 0 ? (mi-L+L1-L2) : 0;
        const int pHi = (mi-L+L1+L2) < 2*L1 ? (mi-L+L1+L2) : 2*L1;
        #pragma unroll
        for(int p=0;p<N1;p++){
            if(p>=pLo && p<=pHi){               // folds at compile time
                const float c = cg[mi*N1+p];
                const int q = mi - L - p + L1 + L2;
                const float2 a=A[p], b=Bv[q];
                aR = fmaf(c, a.x*b.x - a.y*b.y, aR);
                aI = fmaf(c, a.x*b.y + a.y*b.x, aI);
            }
        }
        ff[mi]=make_float2(aR,aI);
    }
}

// ------- kernel 2: variance pass — 8 b's per thread, one atomic each ----------
template<int TR>
__device__ __forceinline__ void var_one(const float2* __restrict__ Fs, int bc, int t){
    constexpr int L=CT_L[TR], L1=CT_L1[TR], L2=CT_L2[TR];
    constexpr int NM=2*L+1;
    const int i=t>>4, j=t&15;
    float n2=0.f;
    for(int b8=0;b8<8;b8++){
        float2 ff[NM];
        cg_compute<L,L1,L2>(Fs + (bc*8+b8)*400, g_cgcD[TR], i, j, ff);
        #pragma unroll
        for(int m=0;m<NM;m++){ n2=fmaf(ff[m].x,ff[m].x,n2); n2=fmaf(ff[m].y,ff[m].y,n2); }
    }
    atomicAdd(&g_varsum[GBASE_t[L] + CT_T[TR]*256 + t], n2);
}

template<int TR>
__device__ __forceinline__ void var_disp(int tr, const float2* Fs, int bc, int t){
    if constexpr (TR < NTRI){
        if(tr==TR) var_one<TR>(Fs,bc,t);
        else       var_disp<TR+1>(tr,Fs,bc,t);
    }
}

__global__ void __launch_bounds__(256) k_var(const float2* __restrict__ Fs){
    var_disp<0>(blockIdx.x, Fs, blockIdx.y, threadIdx.x);
}

// ------- kernel 3: fused CG + BN + matmul, split-K, NON-ATOMIC partials -------
// grid (42, 256) = (triple, b). 256 threads.
template<int TR>
__device__ __forceinline__ void mm_one(const float2* __restrict__ Fs,
                                       const float2* __restrict__ W2,
                                       float2* __restrict__ sh, int b, int t){
    constexpr int L=CT_L[TR], L1=CT_L1[TR], L2=CT_L2[TR], T=CT_T[TR];
    constexpr int NM=2*L+1, K=KL_t[L];
    float2 ff[NM];
    cg_compute<L,L1,L2>(Fs + b*400, g_cgcD[TR], t>>4, t&15, ff);
    const float v = g_varsum[GBASE_t[L] + T*256 + t] * (1.0f/(256.0f*(float)NM));
    const float invv = 1.0f/(sqrtf(v)+1e-5f);
    #pragma unroll
    for(int m=0;m<NM;m++) sh[m*256+t]=make_float2(ff[m].x*invv, ff[m].y*invv);
    __syncthreads();

    const int o=t>>4, sub=t&15;
    const float2* Wrow = W2 + WOFF_t[L] + o*K + T*256;
    float2 acc[NM];
    #pragma unroll
    for(int m=0;m<NM;m++) acc[m]=make_float2(0.f,0.f);
    #pragma unroll
    for(int kk=0;kk<16;kk++){
        const int c2=(kk<<4)+sub;
        const float2 w = Wrow[c2];
        #pragma unroll
        for(int m=0;m<NM;m++){
            const float2 x=sh[m*256+c2];
            acc[m].x = fmaf(w.x,x.x, fmaf(-w.y,x.y, acc[m].x));
            acc[m].y = fmaf(w.x,x.y, fmaf( w.y,x.x, acc[m].y));
        }
    }
    // butterfly reduce over the 16 sub-lanes
    #pragma unroll
    for(int m=0;m<NM;m++){
        #pragma unroll
        for(int s=1;s<16;s<<=1){
            acc[m].x += __shfl_xor(acc[m].x,s,64);
            acc[m].y += __shfl_xor(acc[m].y,s,64);
        }
    }
    if(sub==0){
        float2* pp = g_part + PBASE_t[L] + b*PSTR_t[L] + T*(16*NM) + o*NM;
        #pragma unroll
        for(int m=0;m<NM;m++) pp[m]=acc[m];
    }
}

template<int TR>
__device__ __forceinline__ void mm_disp(int tr, const float2* Fs, const float2* W2,
                                        float2* sh, int b, int t){
    if constexpr (TR < NTRI){
        if(tr==TR) mm_one<TR>(Fs,W2,sh,b,t);
        else       mm_disp<TR+1>(tr,Fs,W2,sh,b,t);
    }
}

__global__ void __launch_bounds__(256) k_mm(const float2* __restrict__ Fs,
                                            const float2* __restrict__ W2){
    __shared__ float2 sh[9*256];
    mm_disp<0>(blockIdx.x, Fs, W2, sh, blockIdx.y, threadIdx.x);
}

// ------- kernel 4: reduce partials over tiles -> out --------------------------
// grid (256 b) x 512 threads; thread r<400 handles out[b*400 + r].
__global__ void __launch_bounds__(512) k_red(float2* __restrict__ out){
    const int b=blockIdx.x, r=threadIdx.x;
    if(r>=400) return;
    const int l = (r<16)?0:(r<64)?1:(r<144)?2:(r<256)?3:4;
    const int om = r - ROFFc[l];            // == o*NM + m by row ordering
    const int nm = NMc[l], nt = NTc[l];
    const float2* pp = g_part + PBASEc[l] + b*PSTRc[l] + om;
    float2 s = make_float2(0.f,0.f);
    for(int T=0;T<nt;T++){
        float2 v = pp[T*16*nm];
        s.x += v.x; s.y += v.y;
    }
    out[b*400 + r] = s;
}

// ---------------- launcher ----------------
extern "C" void kernel_launch(void* const* d_in, const int* in_sizes, int n_in,
                              void* d_out, int out_size, void* d_ws, size_t ws_size,
                              hipStream_t stream){
    const float2* Fs = (const float2*)d_in[0];   // [256,400,2] fp32
    const float2* W  = (const float2*)d_in[1];   // [172032,2]  fp32
    float2* out = (float2*)d_out;                // [256,400,2] fp32

    k_init<<<dim3(NTRI),256,0,stream>>>();
    k_var <<<dim3(NTRI,32),256,0,stream>>>(Fs);
    k_mm  <<<dim3(NTRI,B_SZ),256,0,stream>>>(Fs,W);
    k_red <<<dim3(B_SZ),512,0,stream>>>(out);
}

// Round 7
// 144.645 us; speedup vs baseline: 1.5119x; 1.5119x over previous
//
#include <hip/hip_runtime.h>
#include <math.h>

// ---------------- static problem structure (LMAX=4, taus=16) ----------------
#define NTRI 42
#define NCH  10752
#define B_SZ 256

// triples sorted by (l,l1,l2); CT_T = tile index within degree l
constexpr int CT_L [NTRI]={0,0,0,0,0, 1,1,1,1,1,1,1,1, 2,2,2,2,2,2,2,2,2,2, 3,3,3,3,3,3,3,3,3,3, 4,4,4,4,4,4,4,4,4};
constexpr int CT_L1[NTRI]={0,1,2,3,4, 1,1,2,2,3,3,4,4, 1,2,2,2,3,3,3,4,4,4, 2,2,3,3,3,3,4,4,4,4, 2,3,3,3,4,4,4,4,4};
constexpr int CT_L2[NTRI]={0,1,2,3,4, 0,1,1,2,2,3,3,4, 1,0,1,2,1,2,3,2,3,4, 1,2,0,1,2,3,1,2,3,4, 2,1,2,3,0,1,2,3,4};
constexpr int CT_T [NTRI]={0,1,2,3,4, 0,1,2,3,4,5,6,7, 0,1,2,3,4,5,6,7,8,9, 0,1,2,3,4,5,6,7,8,9, 0,1,2,3,4,5,6,7,8};

constexpr int KL_t[5]    ={1280,2048,2560,2560,2304};   // t_FF[l]
constexpr int GBASE_t[5] ={0,1280,3328,5888,8448};      // channel base
constexpr int ROFF_t[5]  ={0,16,64,144,256};            // row offset in 400-row layout
constexpr int WOFF_t[5]  ={0,20480,53248,94208,135168}; // complex offset into W
constexpr int NT_t[5]    ={5,8,10,10,9};                // tiles per l
constexpr int TRIBASE[5] ={0,5,13,23,33};
constexpr int NM_t[5]    ={1,3,5,7,9};
constexpr int SPL_t[5]   ={1,1,2,3,3};                  // K-splits per l (job balance)
constexpr int POFF_t[5]  ={0,16,64,224,560};            // partial offset within b
#define PSTR 992                                         // partials per b (float2)

// job table: 10 jobs per b, each ~equal phase-B work
constexpr int JOB_L[10]={0,1,2,2,3,3,3,4,4,4};
constexpr int JOB_Z[10]={0,0,0,1,0,1,2,0,1,2};
constexpr int JOB_S[10]={1,1,2,2,3,3,3,3,3,3};

// runtime copies for k_red
__constant__ int ROFFc[5]={0,16,64,144,256};
__constant__ int NMc[5]  ={1,3,5,7,9};
__constant__ int SPLc[5] ={1,1,2,3,3};
__constant__ int POFFc[5]={0,16,64,224,560};

// ---------------- device globals ----------------
__device__ float  g_varsum[NCH];
__device__ float  g_cgcD[NTRI][81];     // dense CG: slot = mi*n1 + p (copied from host)
__device__ float2 g_part[B_SZ*PSTR];    // 2 MB output partials

// ---------------- CG product in registers: thread = pair (i,j) ----------------
template<int L,int L1,int L2>
__device__ __forceinline__ void cg_compute(const float2* __restrict__ FsB,
                                           const float* __restrict__ cg,
                                           int i, int j, float2 (&ff)[2*L+1]){
    constexpr int N1=2*L1+1, N2=2*L2+1, NM=2*L+1;
    float2 A[N1], Bv[N2];
    #pragma unroll
    for(int p=0;p<N1;p++) A[p]=FsB[ROFF_t[L1]+i*N1+p];
    #pragma unroll
    for(int q=0;q<N2;q++) Bv[q]=FsB[ROFF_t[L2]+j*N2+q];
    #pragma unroll
    for(int mi=0;mi<NM;mi++){
        float aR=0.f, aI=0.f;
        const int pLo = (mi-L+L1-L2) > 0 ? (mi-L+L1-L2) : 0;
        const int pHi = (mi-L+L1+L2) < 2*L1 ? (mi-L+L1+L2) : 2*L1;
        #pragma unroll
        for(int p=0;p<N1;p++){
            if(p>=pLo && p<=pHi){               // folds at compile time
                const float c = cg[mi*N1+p];
                const int q = mi - L - p + L1 + L2;
                const float2 a=A[p], b=Bv[q];
                aR = fmaf(c, a.x*b.x - a.y*b.y, aR);
                aI = fmaf(c, a.x*b.y + a.y*b.x, aI);
            }
        }
        ff[mi]=make_float2(aR,aI);
    }
}

// ------- kernel 1: variance pass — 4 b's per thread, one atomic each ----------
template<int TR>
__device__ __forceinline__ void var_one(const float2* __restrict__ Fs, int bc, int t){
    constexpr int L=CT_L[TR], L1=CT_L1[TR], L2=CT_L2[TR];
    constexpr int NM=2*L+1;
    const int i=t>>4, j=t&15;
    float n2=0.f;
    for(int b4=0;b4<4;b4++){
        float2 ff[NM];
        cg_compute<L,L1,L2>(Fs + (bc*4+b4)*400, g_cgcD[TR], i, j, ff);
        #pragma unroll
        for(int m=0;m<NM;m++){ n2=fmaf(ff[m].x,ff[m].x,n2); n2=fmaf(ff[m].y,ff[m].y,n2); }
    }
    atomicAdd(&g_varsum[GBASE_t[L] + CT_T[TR]*256 + t], n2);
}

template<int TR>
__device__ __forceinline__ void var_disp(int tr, const float2* Fs, int bc, int t){
    if constexpr (TR < NTRI){
        if(tr==TR) var_one<TR>(Fs,bc,t);
        else       var_disp<TR+1>(tr,Fs,bc,t);
    }
}

__global__ void __launch_bounds__(256) k_var(const float2* __restrict__ Fs){
    var_disp<0>(blockIdx.x, Fs, blockIdx.y, threadIdx.x);
}

// ------- kernel 2: fused CG + BN + matmul; job-balanced split-K ---------------
// grid (10, 256) = (job, b). Job = (l, z, S): tiles T = z, z+S, ... of degree l.
template<int JL,int JZ,int JS,int T>
__device__ __forceinline__ void job_tiles(const float2* __restrict__ FsB,
                                          const float2* __restrict__ W2,
                                          float2* __restrict__ sh,
                                          float2 (&acc)[2*JL+1], int t){
    if constexpr (T < NT_t[JL]){
        constexpr int TR=TRIBASE[JL]+T;
        constexpr int L1=CT_L1[TR], L2v=CT_L2[TR];
        constexpr int NM=2*JL+1, K=KL_t[JL];
        // phase A: thread = channel t of this tile
        float2 ff[NM];
        cg_compute<JL,L1,L2v>(FsB, g_cgcD[TR], t>>4, t&15, ff);
        const float v = g_varsum[GBASE_t[JL] + T*256 + t] * (1.0f/(256.0f*(float)NM));
        const float invv = 1.0f/(sqrtf(v)+1e-5f);
        __syncthreads();                 // previous tile's phase-B reads done
        #pragma unroll
        for(int m=0;m<NM;m++) sh[m*256+t]=make_float2(ff[m].x*invv, ff[m].y*invv);
        __syncthreads();
        // phase B: thread = (o=t>>4, sub=t&15)
        const int o=t>>4, sub=t&15;
        const float2* Wrow = W2 + WOFF_t[JL] + o*K + T*256;
        #pragma unroll
        for(int kk=0;kk<16;kk++){
            const int c2=(kk<<4)+sub;
            const float2 w = Wrow[c2];
            #pragma unroll
            for(int m=0;m<NM;m++){
                const float2 x=sh[m*256+c2];
                acc[m].x = fmaf(w.x,x.x, fmaf(-w.y,x.y, acc[m].x));
                acc[m].y = fmaf(w.x,x.y, fmaf( w.y,x.x, acc[m].y));
            }
        }
        job_tiles<JL,JZ,JS,T+JS>(FsB,W2,sh,acc,t);
    }
}

template<int J>
__device__ __forceinline__ void job_one(const float2* __restrict__ Fs,
                                        const float2* __restrict__ W2,
                                        float2* __restrict__ sh, int b, int t){
    constexpr int JL=JOB_L[J], JZ=JOB_Z[J], JS=JOB_S[J];
    constexpr int NM=2*JL+1;
    float2 acc[NM];
    #pragma unroll
    for(int m=0;m<NM;m++) acc[m]=make_float2(0.f,0.f);
    job_tiles<JL,JZ,JS,JZ>(Fs + b*400, W2, sh, acc, t);
    // butterfly reduce over the 16 sub-lanes
    #pragma unroll
    for(int m=0;m<NM;m++){
        #pragma unroll
        for(int s=1;s<16;s<<=1){
            acc[m].x += __shfl_xor(acc[m].x,s,64);
            acc[m].y += __shfl_xor(acc[m].y,s,64);
        }
    }
    const int o=t>>4, sub=t&15;
    if(sub==0){
        float2* pp = g_part + b*PSTR + POFF_t[JL] + JZ*(16*NM) + o*NM;
        #pragma unroll
        for(int m=0;m<NM;m++) pp[m]=acc[m];
    }
}

template<int J>
__device__ __forceinline__ void mm_disp(int job, const float2* Fs, const float2* W2,
                                        float2* sh, int b, int t){
    if constexpr (J < 10){
        if(job==J) job_one<J>(Fs,W2,sh,b,t);
        else       mm_disp<J+1>(job,Fs,W2,sh,b,t);
    }
}

__global__ void __launch_bounds__(256) k_mm(const float2* __restrict__ Fs,
                                            const float2* __restrict__ W2){
    __shared__ float2 sh[9*256];
    mm_disp<0>(blockIdx.x, Fs, W2, sh, blockIdx.y, threadIdx.x);
}

// ------- kernel 3: reduce partials over K-splits -> out -----------------------
__global__ void __launch_bounds__(448) k_red(float2* __restrict__ out){
    const int b=blockIdx.x, r=threadIdx.x;
    if(r>=400) return;
    const int l = (r<16)?0:(r<64)?1:(r<144)?2:(r<256)?3:4;
    const int om = r - ROFFc[l];            // == o*NM + m by row ordering
    const int nm=NMc[l], sp=SPLc[l];
    const float2* pp = g_part + b*PSTR + POFFc[l] + om;
    float2 s = make_float2(0.f,0.f);
    for(int z=0; z<sp; z++){
        float2 v = pp[z*16*nm];
        s.x += v.x; s.y += v.y;
    }
    out[b*400 + r] = s;
}

// ---------------- host-side CG table (identical every call; graph-safe) -------
static double h_fact(int n){ double r=1.0; for(int i=2;i<=n;i++) r*=(double)i; return r; }

static double h_cg_coef(int j1,int m1,int j2,int m2,int j,int m){
    if(m1+m2!=m) return 0.0;
    double pref = sqrt((2.0*j+1.0)*h_fact(j+j1-j2)*h_fact(j-j1+j2)*h_fact(j1+j2-j)/h_fact(j1+j2+j+1));
    pref *= sqrt(h_fact(j+m)*h_fact(j-m)*h_fact(j1-m1)*h_fact(j1+m1)*h_fact(j2-m2)*h_fact(j2+m2));
    double s=0.0;
    for(int k=0;k<=j1+j2-j;k++){
        int a=j1-m1-k, bb=j2+m2-k, c=j-j2+m1+k, d=j-j1-m2+k;
        if(a<0||bb<0||c<0||d<0) continue;
        double term = 1.0/(h_fact(k)*h_fact(j1+j2-j-k)*h_fact(a)*h_fact(bb)*h_fact(c)*h_fact(d));
        s += (k&1)? -term : term;
    }
    return pref*s;
}

static float h_cgtab[NTRI][81];   // persists for graph replay

static void build_cg_host(){
    for(int tr=0;tr<NTRI;tr++){
        const int l=CT_L[tr], l1=CT_L1[tr], l2=CT_L2[tr];
        const int nm=2*l+1, n1=2*l1+1;
        for(int s=0;s<81;s++) h_cgtab[tr][s]=0.f;
        for(int mi=0;mi<nm;mi++)
            for(int p=0;p<n1;p++){
                const int m=mi-l, m1=p-l1, m2=m-m1;
                if(m2>=-l2 && m2<=l2)
                    h_cgtab[tr][mi*n1+p]=(float)h_cg_coef(l1,m1,l2,m2,l,m);
            }
    }
}

// ---------------- launcher ----------------
extern "C" void kernel_launch(void* const* d_in, const int* in_sizes, int n_in,
                              void* d_out, int out_size, void* d_ws, size_t ws_size,
                              hipStream_t stream){
    const float2* Fs = (const float2*)d_in[0];   // [256,400,2] fp32
    const float2* W  = (const float2*)d_in[1];   // [172032,2]  fp32
    float2* out = (float2*)d_out;                // [256,400,2] fp32

    build_cg_host();                             // same values every call
    void *dcg=nullptr, *dvs=nullptr;
    hipGetSymbolAddress(&dcg, HIP_SYMBOL(g_cgcD));
    hipGetSymbolAddress(&dvs, HIP_SYMBOL(g_varsum));
    hipMemcpyAsync(dcg, h_cgtab, sizeof(h_cgtab), hipMemcpyHostToDevice, stream);
    hipMemsetAsync(dvs, 0, NCH*sizeof(float), stream);

    k_var<<<dim3(NTRI,64),256,0,stream>>>(Fs);
    k_mm <<<dim3(10,B_SZ),256,0,stream>>>(Fs,W);
    k_red<<<dim3(B_SZ),448,0,stream>>>(out);
}